// Round 9
// baseline (52.378 us; speedup 1.0000x reference)
//
#include <hip/hip_runtime.h>
#include <hip/hip_bf16.h>

// u_dot_v edge scorer: out[e] = dot(x[src[e]], x[dst[e]]), D=64.
// Ladder: fp32 80us -> bf16 46us -> int8 41.5us. r8 lesson: 128B line
// granularity means smaller rows don't cut miss bytes; only miss RATE helps.
// r9: split dot over feature halves. Each pass gathers a CONTIGUOUS 3.2MB
// int8 array (fits 4MB per-XCD L2) -> near-compulsory misses. Pass1 writes
// exact int32 partials into d_out (bit-cast); pass2 adds its half and scales
// by sinv[src]*sinv[dst]. Same quantization as r8 -> same absmax 0.44.

// ---- quantize: x fp32 [N][64] -> xq_lo [N][32] + xq_hi [N][32] + sinv [N]
__global__ __launch_bounds__(256) void quantize_i8_split_kernel(
    const float* __restrict__ x, signed char* __restrict__ xq_lo,
    signed char* __restrict__ xq_hi, float* __restrict__ sinv, int n_rows) {
  int tid = blockIdx.x * blockDim.x + threadIdx.x;
  int row = tid >> 3;
  int lane = tid & 7;   // lane covers elems 8*lane .. 8*lane+7
  if (row >= n_rows) return;

  const float4* xr = reinterpret_cast<const float4*>(x + (size_t)row * 64);
  float4 v0 = xr[lane * 2];
  float4 v1 = xr[lane * 2 + 1];

  float m = fmaxf(fmaxf(fmaxf(fabsf(v0.x), fabsf(v0.y)),
                        fmaxf(fabsf(v0.z), fabsf(v0.w))),
                  fmaxf(fmaxf(fabsf(v1.x), fabsf(v1.y)),
                        fmaxf(fabsf(v1.z), fabsf(v1.w))));
  m = fmaxf(m, __shfl_xor(m, 1, 64));
  m = fmaxf(m, __shfl_xor(m, 2, 64));
  m = fmaxf(m, __shfl_xor(m, 4, 64));

  float s = (m > 0.f) ? 127.f / m : 0.f;

  int q0 = __float2int_rn(v0.x * s), q1 = __float2int_rn(v0.y * s);
  int q2 = __float2int_rn(v0.z * s), q3 = __float2int_rn(v0.w * s);
  int q4 = __float2int_rn(v1.x * s), q5 = __float2int_rn(v1.y * s);
  int q6 = __float2int_rn(v1.z * s), q7 = __float2int_rn(v1.w * s);

  unsigned lo = (q0 & 255) | ((q1 & 255) << 8) | ((q2 & 255) << 16) | ((q3 & 255) << 24);
  unsigned hi = (q4 & 255) | ((q5 & 255) << 8) | ((q6 & 255) << 16) | ((q7 & 255) << 24);
  uint2 pk; pk.x = lo; pk.y = hi;

  signed char* base = (lane < 4) ? xq_lo : xq_hi;
  reinterpret_cast<uint2*>(base + (size_t)row * 32)[lane & 3] = pk;

  if (lane == 0) sinv[row] = (m > 0.f) ? m / 127.f : 0.f;
}

// ---- int8 dot helpers ----
__device__ __forceinline__ int dot4i8(unsigned a, unsigned b, int c) {
#if __has_builtin(__builtin_amdgcn_sdot4)
  return __builtin_amdgcn_sdot4((int)a, (int)b, c, false);
#else
  c += (int)(signed char)(a)       * (int)(signed char)(b);
  c += (int)(signed char)(a >> 8)  * (int)(signed char)(b >> 8);
  c += (int)(signed char)(a >> 16) * (int)(signed char)(b >> 16);
  c += (int)(signed char)(a >> 24) * (int)(signed char)(b >> 24);
  return c;
#endif
}

__device__ __forceinline__ int dot16i8(uint4 a, uint4 b) {
  int c = dot4i8(a.x, b.x, 0);
  c = dot4i8(a.y, b.y, c);
  c = dot4i8(a.z, b.z, c);
  c = dot4i8(a.w, b.w, c);
  return c;
}

// ---- gather pass over one feature half (32 int8 = 32B = 2 x uint4/row).
// 2 lanes/edge, 4 edges per 2-lane group -> 8 independent 16B gathers/lane.
// PHASE 0: write exact int32 partials (bit-cast) into out.
// PHASE 1: read partials, add, scale, store float4.
template <int PHASE>
__global__ __launch_bounds__(256) void edge_dot_i8_half_kernel(
    const signed char* __restrict__ xqh,
    const float* __restrict__ sinv,
    const int* __restrict__ src,
    const int* __restrict__ dst,
    float* __restrict__ out,
    int n_edges) {
  int tid = blockIdx.x * blockDim.x + threadIdx.x;
  int gid = tid >> 1;        // 2-lane group
  int lane = tid & 1;
  int e0 = gid << 2;         // 4 edges per group; E % 4 == 0
  if (e0 >= n_edges) return;

  int4 si = *reinterpret_cast<const int4*>(src + e0);
  int4 di = *reinterpret_cast<const int4*>(dst + e0);

  uint4 a0 = *(reinterpret_cast<const uint4*>(xqh + (size_t)si.x * 32) + lane);
  uint4 a1 = *(reinterpret_cast<const uint4*>(xqh + (size_t)si.y * 32) + lane);
  uint4 a2 = *(reinterpret_cast<const uint4*>(xqh + (size_t)si.z * 32) + lane);
  uint4 a3 = *(reinterpret_cast<const uint4*>(xqh + (size_t)si.w * 32) + lane);
  uint4 b0 = *(reinterpret_cast<const uint4*>(xqh + (size_t)di.x * 32) + lane);
  uint4 b1 = *(reinterpret_cast<const uint4*>(xqh + (size_t)di.y * 32) + lane);
  uint4 b2 = *(reinterpret_cast<const uint4*>(xqh + (size_t)di.z * 32) + lane);
  uint4 b3 = *(reinterpret_cast<const uint4*>(xqh + (size_t)di.w * 32) + lane);

  int s0 = dot16i8(a0, b0);
  int s1 = dot16i8(a1, b1);
  int s2 = dot16i8(a2, b2);
  int s3 = dot16i8(a3, b3);

  s0 += __shfl_xor(s0, 1, 64);
  s1 += __shfl_xor(s1, 1, 64);
  s2 += __shfl_xor(s2, 1, 64);
  s3 += __shfl_xor(s3, 1, 64);

  if (lane == 0) {
    if (PHASE == 0) {
      int4 r; r.x = s0; r.y = s1; r.z = s2; r.w = s3;
      *reinterpret_cast<int4*>(out + e0) = r;   // int bits in f32 buffer
    } else {
      int4 p = *reinterpret_cast<const int4*>(out + e0);
      float r0 = (float)(p.x + s0) * sinv[si.x] * sinv[di.x];
      float r1 = (float)(p.y + s1) * sinv[si.y] * sinv[di.y];
      float r2 = (float)(p.z + s2) * sinv[si.z] * sinv[di.z];
      float r3 = (float)(p.w + s3) * sinv[si.w] * sinv[di.w];
      *reinterpret_cast<float4*>(out + e0) = make_float4(r0, r1, r2, r3);
    }
  }
}

// Fallback: fp32 gather, used only if ws too small for quantized copy of x.
__global__ __launch_bounds__(256) void edge_dot_f32_kernel(
    const float* __restrict__ x,
    const int* __restrict__ src,
    const int* __restrict__ dst,
    float* __restrict__ out,
    int n_edges) {
  int tid = blockIdx.x * blockDim.x + threadIdx.x;
  int edge = tid >> 4;
  int lane = tid & 15;
  if (edge >= n_edges) return;
  int s = src[edge];
  int d = dst[edge];
  float4 a = reinterpret_cast<const float4*>(x + (size_t)s * 64)[lane];
  float4 b = reinterpret_cast<const float4*>(x + (size_t)d * 64)[lane];
  float acc = a.x * b.x + a.y * b.y + a.z * b.z + a.w * b.w;
  acc += __shfl_xor(acc, 1, 64);
  acc += __shfl_xor(acc, 2, 64);
  acc += __shfl_xor(acc, 4, 64);
  acc += __shfl_xor(acc, 8, 64);
  if (lane == 0) out[edge] = acc;
}

extern "C" void kernel_launch(void* const* d_in, const int* in_sizes, int n_in,
                              void* d_out, int out_size, void* d_ws, size_t ws_size,
                              hipStream_t stream) {
  const float* x = (const float*)d_in[0];
  const int* src = (const int*)d_in[1];
  const int* dst = (const int*)d_in[2];
  float* out = (float*)d_out;

  int n_feat_total = in_sizes[0];      // N * D
  int n_edges = in_sizes[1];           // E
  int n_rows = n_feat_total / 64;      // D = 64

  size_t half_bytes = (size_t)n_rows * 32;            // int8 half
  size_t sinv_bytes = (size_t)n_rows * sizeof(float);

  if (ws_size >= 2 * half_bytes + sinv_bytes) {
    signed char* xq_lo = (signed char*)d_ws;
    signed char* xq_hi = xq_lo + half_bytes;
    float* sinv = (float*)((char*)d_ws + 2 * half_bytes);

    int qthreads = n_rows * 8;
    quantize_i8_split_kernel<<<(qthreads + 255) / 256, 256, 0, stream>>>(
        x, xq_lo, xq_hi, sinv, n_rows);

    // 2 lanes/edge-quad-group: E/4 groups * 2 threads = E/2 threads per pass.
    long long threads_total = (long long)((n_edges + 3) / 4) * 2;
    int grid = (int)((threads_total + 255) / 256);
    edge_dot_i8_half_kernel<0><<<grid, 256, 0, stream>>>(
        xq_lo, sinv, src, dst, out, n_edges);
    edge_dot_i8_half_kernel<1><<<grid, 256, 0, stream>>>(
        xq_hi, sinv, src, dst, out, n_edges);
  } else {
    long long threads_total = (long long)n_edges * 16;
    int grid = (int)((threads_total + 255) / 256);
    edge_dot_f32_kernel<<<grid, 256, 0, stream>>>(x, src, dst, out, n_edges);
  }
}

// Round 10
// 41.608 us; speedup vs baseline: 1.2588x; 1.2588x over previous
//
#include <hip/hip_runtime.h>
#include <hip/hip_bf16.h>

// u_dot_v edge scorer: out[e] = dot(x[src[e]], x[dst[e]]), D=64.
// Ladder: fp32 80us -> bf16 46us -> int8 41.5us (BEST, this kernel).
// Failed branches: nt hints (r5/r6, +3-5us), feature-split two-pass (r9,
// +11us: 128B line granularity means a 32B-row miss still pulls 128B, and
// the split doubles index traffic). Bottleneck: random-gather line traffic
// on the L2-miss path at ~3.5 TB/s; at 64B rows the working set (6.8MB)
// vs 4MB/XCD L2 sets the miss rate. This is within ~5% of the structural
// floor for this access pattern.

// ---- quantize: x fp32 [N][64] -> xq int8 [N][64] + sinv fp32 [N] ----
// 8 lanes per row; each lane handles 8 consecutive floats.
__global__ __launch_bounds__(256) void quantize_i8_kernel(
    const float* __restrict__ x, signed char* __restrict__ xq,
    float* __restrict__ sinv, int n_rows) {
  int tid = blockIdx.x * blockDim.x + threadIdx.x;
  int row = tid >> 3;
  int lane = tid & 7;
  if (row >= n_rows) return;

  const float4* xr = reinterpret_cast<const float4*>(x + (size_t)row * 64);
  float4 v0 = xr[lane * 2];
  float4 v1 = xr[lane * 2 + 1];

  float m = fmaxf(fmaxf(fmaxf(fabsf(v0.x), fabsf(v0.y)),
                        fmaxf(fabsf(v0.z), fabsf(v0.w))),
                  fmaxf(fmaxf(fabsf(v1.x), fabsf(v1.y)),
                        fmaxf(fabsf(v1.z), fabsf(v1.w))));
  m = fmaxf(m, __shfl_xor(m, 1, 64));
  m = fmaxf(m, __shfl_xor(m, 2, 64));
  m = fmaxf(m, __shfl_xor(m, 4, 64));

  float s = (m > 0.f) ? 127.f / m : 0.f;

  int q0 = __float2int_rn(v0.x * s), q1 = __float2int_rn(v0.y * s);
  int q2 = __float2int_rn(v0.z * s), q3 = __float2int_rn(v0.w * s);
  int q4 = __float2int_rn(v1.x * s), q5 = __float2int_rn(v1.y * s);
  int q6 = __float2int_rn(v1.z * s), q7 = __float2int_rn(v1.w * s);

  unsigned lo = (q0 & 255) | ((q1 & 255) << 8) | ((q2 & 255) << 16) | ((q3 & 255) << 24);
  unsigned hi = (q4 & 255) | ((q5 & 255) << 8) | ((q6 & 255) << 16) | ((q7 & 255) << 24);
  uint2 pk; pk.x = lo; pk.y = hi;
  reinterpret_cast<uint2*>(xq + (size_t)row * 64)[lane] = pk;

  if (lane == 0) sinv[row] = (m > 0.f) ? m / 127.f : 0.f;
}

// ---- int8 dot helpers ----
__device__ __forceinline__ int dot4i8(unsigned a, unsigned b, int c) {
#if __has_builtin(__builtin_amdgcn_sdot4)
  return __builtin_amdgcn_sdot4((int)a, (int)b, c, false);
#else
  c += (int)(signed char)(a)       * (int)(signed char)(b);
  c += (int)(signed char)(a >> 8)  * (int)(signed char)(b >> 8);
  c += (int)(signed char)(a >> 16) * (int)(signed char)(b >> 16);
  c += (int)(signed char)(a >> 24) * (int)(signed char)(b >> 24);
  return c;
#endif
}

__device__ __forceinline__ int dot16i8(uint4 a, uint4 b) {
  int c = dot4i8(a.x, b.x, 0);
  c = dot4i8(a.y, b.y, c);
  c = dot4i8(a.z, b.z, c);
  c = dot4i8(a.w, b.w, c);
  return c;
}

// ---- gather: 4 lanes/edge (row = 64B = 4 x uint4), 4 edges per 4-lane
// group -> 8 independent 16B gathers in flight per lane. Exact int32 dot,
// butterfly reduce over the 4-lane group, lane-0 scales and stores float4.
__global__ __launch_bounds__(256) void edge_dot_i8_kernel(
    const signed char* __restrict__ xq,
    const float* __restrict__ sinv,
    const int* __restrict__ src,
    const int* __restrict__ dst,
    float* __restrict__ out,
    int n_edges) {
  int tid = blockIdx.x * blockDim.x + threadIdx.x;
  int gid = tid >> 2;        // 4-lane group
  int lane = tid & 3;
  int e0 = gid << 2;         // 4 edges per group; E % 4 == 0
  if (e0 >= n_edges) return;

  int4 si = *reinterpret_cast<const int4*>(src + e0);
  int4 di = *reinterpret_cast<const int4*>(dst + e0);

  uint4 a0 = *(reinterpret_cast<const uint4*>(xq + (size_t)si.x * 64) + lane);
  uint4 a1 = *(reinterpret_cast<const uint4*>(xq + (size_t)si.y * 64) + lane);
  uint4 a2 = *(reinterpret_cast<const uint4*>(xq + (size_t)si.z * 64) + lane);
  uint4 a3 = *(reinterpret_cast<const uint4*>(xq + (size_t)si.w * 64) + lane);
  uint4 b0 = *(reinterpret_cast<const uint4*>(xq + (size_t)di.x * 64) + lane);
  uint4 b1 = *(reinterpret_cast<const uint4*>(xq + (size_t)di.y * 64) + lane);
  uint4 b2 = *(reinterpret_cast<const uint4*>(xq + (size_t)di.z * 64) + lane);
  uint4 b3 = *(reinterpret_cast<const uint4*>(xq + (size_t)di.w * 64) + lane);

  int s0 = dot16i8(a0, b0);
  int s1 = dot16i8(a1, b1);
  int s2 = dot16i8(a2, b2);
  int s3 = dot16i8(a3, b3);

  // exact int butterfly reduce over the 4-lane group
  s0 += __shfl_xor(s0, 1, 64); s0 += __shfl_xor(s0, 2, 64);
  s1 += __shfl_xor(s1, 1, 64); s1 += __shfl_xor(s1, 2, 64);
  s2 += __shfl_xor(s2, 1, 64); s2 += __shfl_xor(s2, 2, 64);
  s3 += __shfl_xor(s3, 1, 64); s3 += __shfl_xor(s3, 2, 64);

  if (lane == 0) {
    float r0 = (float)s0 * sinv[si.x] * sinv[di.x];
    float r1 = (float)s1 * sinv[si.y] * sinv[di.y];
    float r2 = (float)s2 * sinv[si.z] * sinv[di.z];
    float r3 = (float)s3 * sinv[si.w] * sinv[di.w];
    *reinterpret_cast<float4*>(out + e0) = make_float4(r0, r1, r2, r3);
  }
}

// Fallback: fp32 gather, used only if ws too small for quantized copy of x.
__global__ __launch_bounds__(256) void edge_dot_f32_kernel(
    const float* __restrict__ x,
    const int* __restrict__ src,
    const int* __restrict__ dst,
    float* __restrict__ out,
    int n_edges) {
  int tid = blockIdx.x * blockDim.x + threadIdx.x;
  int edge = tid >> 4;
  int lane = tid & 15;
  if (edge >= n_edges) return;
  int s = src[edge];
  int d = dst[edge];
  float4 a = reinterpret_cast<const float4*>(x + (size_t)s * 64)[lane];
  float4 b = reinterpret_cast<const float4*>(x + (size_t)d * 64)[lane];
  float acc = a.x * b.x + a.y * b.y + a.z * b.z + a.w * b.w;
  acc += __shfl_xor(acc, 1, 64);
  acc += __shfl_xor(acc, 2, 64);
  acc += __shfl_xor(acc, 4, 64);
  acc += __shfl_xor(acc, 8, 64);
  if (lane == 0) out[edge] = acc;
}

extern "C" void kernel_launch(void* const* d_in, const int* in_sizes, int n_in,
                              void* d_out, int out_size, void* d_ws, size_t ws_size,
                              hipStream_t stream) {
  const float* x = (const float*)d_in[0];
  const int* src = (const int*)d_in[1];
  const int* dst = (const int*)d_in[2];
  float* out = (float*)d_out;

  int n_feat_total = in_sizes[0];      // N * D
  int n_edges = in_sizes[1];           // E
  int n_rows = n_feat_total / 64;      // D = 64

  size_t xq_bytes = (size_t)n_feat_total;           // int8
  size_t sinv_bytes = (size_t)n_rows * sizeof(float);

  if (ws_size >= xq_bytes + sinv_bytes) {
    signed char* xq = (signed char*)d_ws;
    float* sinv = (float*)((char*)d_ws + xq_bytes);

    int qthreads = n_rows * 8;
    quantize_i8_kernel<<<(qthreads + 255) / 256, 256, 0, stream>>>(x, xq, sinv, n_rows);

    // 4 lanes/edge, 4 edges per group -> 1 thread per edge total.
    int grid = (n_edges + 255) / 256;
    edge_dot_i8_kernel<<<grid, 256, 0, stream>>>(xq, sinv, src, dst, out, n_edges);
  } else {
    long long threads_total = (long long)n_edges * 16;
    int grid = (int)((threads_total + 255) / 256);
    edge_dot_f32_kernel<<<grid, 256, 0, stream>>>(x, src, dst, out, n_edges);
  }
}